// Round 6
// baseline (1712.882 us; speedup 1.0000x reference)
//
#include <hip/hip_runtime.h>

#define NN 100000
#define EE 1600000
#define DTc 0.1f
#define REGc 1e-6f
#define WQc (1.0f / 64.0f)

#define NB 782              // ceil(NN/128) buckets of 128 nodes
#define CHUNK 8192          // edges per binning block
#define NCH 196             // ceil(EE/CHUNK)
#define SC_NB 300           // scan blocks of 512 over the matrix
#define MPAD (SC_NB * 512)  // 153600 >= NB*NCH = 153272
#define TENT (2 * EE)       // combined incidence entries
#define ACT_S 72            // padded LDS row stride (bf16) in node_kernel

typedef unsigned long long u64;
typedef __attribute__((ext_vector_type(8))) short short8;
typedef __attribute__((ext_vector_type(4))) float f32x4;

__device__ __forceinline__ unsigned short f2bf(float x) {
    unsigned u = __float_as_uint(x);
    unsigned r = (u + 0x7fffu + ((u >> 16) & 1u)) >> 16;   // RNE
    return (unsigned short)r;
}
__device__ __forceinline__ float bf2f(unsigned short s) {
    return __uint_as_float(((unsigned)s) << 16);
}

// ---------------------------------------------------------------------------
// f+ = relu(f) as bf16, 4 elems/thread (NN*16 threads)
// ---------------------------------------------------------------------------
__global__ __launch_bounds__(256) void pre_kernel(const float* __restrict__ f,
                                                  unsigned int* __restrict__ fb16u) {
    int i = blockIdx.x * 256 + threadIdx.x;
    if (i < NN * 16) {
        float4 v = *(const float4*)&f[i * 4];
        unsigned lo = (unsigned)f2bf(fmaxf(v.x, 0.f)) | ((unsigned)f2bf(fmaxf(v.y, 0.f)) << 16);
        unsigned hi = (unsigned)f2bf(fmaxf(v.z, 0.f)) | ((unsigned)f2bf(fmaxf(v.w, 0.f)) << 16);
        fb16u[i * 2] = lo;
        fb16u[i * 2 + 1] = hi;
    }
}

// ---------------------------------------------------------------------------
// Weight prep: wp[l][n*64+k] = bf16(W_l[k*64+n])  (transposed, B-frag ready)
// ---------------------------------------------------------------------------
__global__ __launch_bounds__(256) void wprep_kernel(
    const float* __restrict__ w_in, const float* __restrict__ w_hid,
    const float* __restrict__ w_out, unsigned short* __restrict__ wp) {
    int i = blockIdx.x * 256 + threadIdx.x;
    if (i < 5 * 4096) {
        int l = i >> 12, idx = i & 4095;
        int n = idx >> 6, k = idx & 63;
        const float* W = (l == 0) ? w_in : (l < 4 ? w_hid + (l - 1) * 4096 : w_out);
        wp[i] = f2bf(W[k * 64 + n]);
    }
}

// ---------------------------------------------------------------------------
// Out-degree histogram (for q = ew/deg[src])
// ---------------------------------------------------------------------------
__global__ __launch_bounds__(256) void hist_kernel(const int* __restrict__ esrc,
                                                   int* __restrict__ deg) {
    int i = blockIdx.x * 256 + threadIdx.x;
    if (i < EE) atomicAdd(&deg[esrc[i]], 1);
}

// ---------------------------------------------------------------------------
// Per-chunk bucket counts -> bucket-major matrix bc[bucket*NCH + chunk]
// ---------------------------------------------------------------------------
__global__ __launch_bounds__(256) void bin_count(const int* __restrict__ esrc,
                                                 const int* __restrict__ edst,
                                                 int* __restrict__ bc) {
    __shared__ int cnt[NB];
    int t = threadIdx.x;
    for (int j = t; j < NB; j += 256) cnt[j] = 0;
    __syncthreads();
    int base = blockIdx.x * CHUNK;
    int nE = min(CHUNK, EE - base);
    for (int i = t; i < nE; i += 256) {
        atomicAdd(&cnt[esrc[base + i] >> 7], 1);
        atomicAdd(&cnt[edst[base + i] >> 7], 1);
    }
    __syncthreads();
    for (int j = t; j < NB; j += 256) bc[j * NCH + blockIdx.x] = cnt[j];
}

// ---------------------------------------------------------------------------
// 3-kernel exclusive scan over MPAD elements (pad pre-zeroed by memset)
// ---------------------------------------------------------------------------
__global__ __launch_bounds__(512) void scan_blocks(const int* __restrict__ in,
                                                   int* __restrict__ out,
                                                   int* __restrict__ bsums) {
    __shared__ int s[512];
    int t = threadIdx.x;
    int i = blockIdx.x * 512 + t;
    int v = in[i];
    s[t] = v;
    __syncthreads();
    for (int o = 1; o < 512; o <<= 1) {
        int x = (t >= o) ? s[t - o] : 0;
        __syncthreads();
        s[t] += x;
        __syncthreads();
    }
    out[i] = s[t] - v;
    if (t == 0) bsums[blockIdx.x] = s[511];
}

__global__ __launch_bounds__(512) void scan_sums(int* __restrict__ bsums) {
    __shared__ int s[512];
    int t = threadIdx.x;
    int v = (t < SC_NB) ? bsums[t] : 0;
    s[t] = v;
    __syncthreads();
    for (int o = 1; o < 512; o <<= 1) {
        int x = (t >= o) ? s[t - o] : 0;
        __syncthreads();
        s[t] += x;
        __syncthreads();
    }
    if (t < SC_NB) bsums[t] = s[t] - v;
}

__global__ __launch_bounds__(512) void add_offsets(int* __restrict__ offs,
                                                   const int* __restrict__ bsums) {
    int i = blockIdx.x * 512 + threadIdx.x;
    offs[i] += bsums[blockIdx.x];
}

// ---------------------------------------------------------------------------
// Binned scatter: chunk re-reads its edges, appends entries into its PRIVATE
// [chunk][bucket] ranges via LDS cursors. entry = (f32 q)<<32 | local<<17 | other
// ---------------------------------------------------------------------------
__global__ __launch_bounds__(256) void bin_scatter(
    const int* __restrict__ esrc, const int* __restrict__ edst,
    const float* __restrict__ ew, const int* __restrict__ deg,
    const int* __restrict__ offs, u64* __restrict__ adj64) {
    __shared__ int cur[NB];
    int t = threadIdx.x, blk = blockIdx.x;
    for (int j = t; j < NB; j += 256) cur[j] = offs[j * NCH + blk];
    __syncthreads();
    int base = blk * CHUNK;
    int nE = min(CHUNK, EE - base);
    for (int i = t; i < nE; i += 256) {
        int s = esrc[base + i], d = edst[base + i];
        float q = ew[base + i] / (float)deg[s];
        u64 qb = ((u64)__float_as_uint(q)) << 32;
        int p1 = atomicAdd(&cur[s >> 7], 1);
        adj64[p1] = qb | (unsigned)(d | ((s & 127) << 17));
        int p2 = atomicAdd(&cur[d >> 7], 1);
        adj64[p2] = qb | (unsigned)(s | ((d & 127) << 17));
    }
}

// ---------------------------------------------------------------------------
// Gather transport per 128-node bucket with LDS fp32 accumulator.
// One wave per entry (lane = velocity bin), unroll-4; OOB slots -> e=0 -> q=0.
// trans[n] = xi * (sum q_j f+[other_j] - (sum q_j) f+[n])
// ---------------------------------------------------------------------------
__global__ __launch_bounds__(256) void gather_bucket(
    const unsigned short* __restrict__ fb16, const int* __restrict__ offs,
    const u64* __restrict__ adj64, const float* __restrict__ xi,
    float* __restrict__ trans) {
    __shared__ float acc[128 * 64];   // 32 KB
    __shared__ float qsum[128];
    __shared__ float xif[64];
    int t = threadIdx.x, b = blockIdx.x;
    int lane = t & 63, wid = t >> 6;
    for (int j = t; j < 8192; j += 256) acc[j] = 0.f;
    if (t < 128) qsum[t] = 0.f;
    if (t < 64) xif[t] = xi[t];
    __syncthreads();
    int start = offs[b * NCH];
    int end = offs[(b + 1) * NCH];
    for (int i = start + wid * 4; i < end; i += 16) {
        u64 e0 = (i + 0 < end) ? adj64[i + 0] : 0ull;
        u64 e1 = (i + 1 < end) ? adj64[i + 1] : 0ull;
        u64 e2 = (i + 2 < end) ? adj64[i + 2] : 0ull;
        u64 e3 = (i + 3 < end) ? adj64[i + 3] : 0ull;
        float f0 = bf2f(fb16[((unsigned)e0 & 0x1FFFFu) * 64 + lane]);
        float f1 = bf2f(fb16[((unsigned)e1 & 0x1FFFFu) * 64 + lane]);
        float f2 = bf2f(fb16[((unsigned)e2 & 0x1FFFFu) * 64 + lane]);
        float f3 = bf2f(fb16[((unsigned)e3 & 0x1FFFFu) * 64 + lane]);
        float q0 = __uint_as_float((unsigned)(e0 >> 32));
        float q1 = __uint_as_float((unsigned)(e1 >> 32));
        float q2 = __uint_as_float((unsigned)(e2 >> 32));
        float q3 = __uint_as_float((unsigned)(e3 >> 32));
        int l0 = ((unsigned)e0 >> 17) & 127;
        int l1 = ((unsigned)e1 >> 17) & 127;
        int l2 = ((unsigned)e2 >> 17) & 127;
        int l3 = ((unsigned)e3 >> 17) & 127;
        atomicAdd(&acc[l0 * 64 + lane], q0 * f0);
        atomicAdd(&acc[l1 * 64 + lane], q1 * f1);
        atomicAdd(&acc[l2 * 64 + lane], q2 * f2);
        atomicAdd(&acc[l3 * 64 + lane], q3 * f3);
        if (lane == 0) {
            atomicAdd(&qsum[l0], q0);
            atomicAdd(&qsum[l1], q1);
            atomicAdd(&qsum[l2], q2);
            atomicAdd(&qsum[l3], q3);
        }
    }
    __syncthreads();
    // finalize: trans rows for this bucket's nodes
    for (int k = 0; k < 32; k++) {
        int e = k * 256 + t;
        int local = e >> 6, bin = e & 63;
        int n = b * 128 + local;
        if (n < NN) {
            float fn = bf2f(fb16[n * 64 + bin]);
            trans[n * 64 + bin] = xif[bin] * (acc[e] - qsum[local] * fn);
        }
    }
}

// ---------------------------------------------------------------------------
// MFMA node kernel (unchanged from R5): 256 thr / 4 waves / 128 nodes.
// ---------------------------------------------------------------------------
__global__ __launch_bounds__(256) void node_kernel(
    const unsigned short* __restrict__ fb16, const float* __restrict__ f,
    const float* __restrict__ macro_u, const float* __restrict__ source,
    const float* __restrict__ xi, const unsigned short* __restrict__ wp,
    const float* __restrict__ b_in, const float* __restrict__ b_hid,
    const float* __restrict__ b_out,
    const float* __restrict__ trans, float* __restrict__ out) {
    __shared__ __attribute__((aligned(16))) unsigned short act[128 * ACT_S];
    __shared__ float s0s[128], s1s[128], us[128], xif[64];

    const int t = threadIdx.x;
    const int wid = t >> 6;
    const int lane = t & 63;
    const int m = lane & 15;
    const int quad = lane >> 4;
    const int nodeBase = blockIdx.x * 128;
    const int gbase = nodeBase * 64;

    if (t < 128) {
        int n = nodeBase + t;
        us[t] = (n < NN) ? macro_u[n] : 0.f;
    }
    if (t < 64) xif[t] = xi[t];

#pragma unroll
    for (int i = 0; i < 8; i++) {
        int r = wid * 32 + i * 4 + (lane >> 4);
        int c = (lane & 15) * 4;
        uint2 v = {0u, 0u};
        if (nodeBase + r < NN) v = *(const uint2*)&fb16[gbase + r * 64 + c];
        *(uint2*)&act[r * ACT_S + c] = v;
    }

    const int rowbase = wid * 32;

    for (int l = 0; l < 5; l++) {
        const unsigned short* W = wp + l * 4096;
        const float* B = (l == 0) ? b_in : (l < 4 ? b_hid + (l - 1) * 64 : b_out);

        short8 Af[2][2], Bf[4][2];
#pragma unroll
        for (int rt = 0; rt < 2; rt++)
#pragma unroll
            for (int kk = 0; kk < 2; kk++)
                Af[rt][kk] = *(const short8*)&act[(rowbase + rt * 16 + m) * ACT_S + kk * 32 + quad * 8];
#pragma unroll
        for (int ct = 0; ct < 4; ct++)
#pragma unroll
            for (int kk = 0; kk < 2; kk++)
                Bf[ct][kk] = *(const short8*)&W[(ct * 16 + m) * 64 + kk * 32 + quad * 8];

        f32x4 acc[2][4];
#pragma unroll
        for (int rt = 0; rt < 2; rt++)
#pragma unroll
            for (int ct = 0; ct < 4; ct++) {
                acc[rt][ct] = (f32x4){0.f, 0.f, 0.f, 0.f};
                acc[rt][ct] = __builtin_amdgcn_mfma_f32_16x16x32_bf16(Af[rt][0], Bf[ct][0], acc[rt][ct], 0, 0, 0);
                acc[rt][ct] = __builtin_amdgcn_mfma_f32_16x16x32_bf16(Af[rt][1], Bf[ct][1], acc[rt][ct], 0, 0, 0);
            }

#pragma unroll
        for (int rt = 0; rt < 2; rt++)
#pragma unroll
            for (int ct = 0; ct < 4; ct++) {
                float bv = B[ct * 16 + m];
#pragma unroll
                for (int r = 0; r < 4; r++) {
                    int row = rowbase + rt * 16 + quad * 4 + r;
                    float val = acc[rt][ct][r] + bv;
                    val = (l < 4) ? fmaxf(val, 0.f) : tanhf(val);
                    act[row * ACT_S + ct * 16 + m] = f2bf(val);
                }
            }
    }
    __syncthreads();

    if (t < 128) {
        float u = us[t];
        float v0 = 0.f, v1 = 0.f, sxs2 = 0.f, sxi = 0.f;
        const short8* rp = (const short8*)&act[t * ACT_S];
#pragma unroll
        for (int c = 0; c < 8; c++) {
            short8 v = rp[c];
#pragma unroll
            for (int jj = 0; jj < 8; jj++) {
                float om = bf2f((unsigned short)v[jj]);
                float xv = xif[c * 8 + jj];
                float xs = xv + u;
                v0 += om;
                v1 += xs * om;
                sxs2 += xs * xs;
                sxi += xv;
            }
        }
        v0 *= WQc;
        v1 *= WQc;
        float c00 = WQc + REGc;
        float c01 = WQc * WQc * (sxi + 64.f * u);
        float c11 = WQc * WQc * sxs2 + REGc;
        float det = c00 * c11 - c01 * c01;
        float inv = 1.0f / det;
        s0s[t] = (c11 * v0 - c01 * v1) * inv;
        s1s[t] = (c00 * v1 - c01 * v0) * inv;
    }
    __syncthreads();

#pragma unroll
    for (int i = 0; i < 8; i++) {
        int e = (i * 256 + t) * 4;
        int nl = e >> 6;
        if (nodeBase + nl < NN) {
            int g = gbase + e;
            int c0 = e & 63;
            float4 fv = *(const float4*)&f[g];
            float4 sv = *(const float4*)&source[g];
            float4 tv = *(const float4*)&trans[g];
            float uu = us[nl];
            float sv0 = s0s[nl], sv1 = s1s[nl];
            float4 ov;
            float* ovp = (float*)&ov;
            const float* fp = (const float*)&fv;
            const float* sp = (const float*)&sv;
            const float* tp = (const float*)&tv;
#pragma unroll
            for (int jj = 0; jj < 4; jj++) {
                float om = bf2f(act[nl * ACT_S + c0 + jj]);
                float xs = xif[c0 + jj] + uu;
                float omst = om - WQc * (sv0 + xs * sv1);
                float val = fmaxf(fp[jj], 0.f) + DTc * (sp[jj] + omst - tp[jj]);
                ovp[jj] = fmaxf(val, 0.f);
            }
            *(float4*)&out[g] = ov;
        }
    }
}

extern "C" void kernel_launch(void* const* d_in, const int* in_sizes, int n_in,
                              void* d_out, int out_size, void* d_ws, size_t ws_size,
                              hipStream_t stream) {
    const float* f       = (const float*)d_in[0];
    const float* macro_u = (const float*)d_in[1];
    const float* source  = (const float*)d_in[2];
    const int*   esrc    = (const int*)d_in[3];
    const int*   edst    = (const int*)d_in[4];
    const float* ew      = (const float*)d_in[5];
    const float* xi      = (const float*)d_in[6];
    const float* w_in    = (const float*)d_in[7];
    const float* b_in    = (const float*)d_in[8];
    const float* w_hid   = (const float*)d_in[9];
    const float* b_hid   = (const float*)d_in[10];
    const float* w_out   = (const float*)d_in[11];
    const float* b_out   = (const float*)d_in[12];
    float* out = (float*)d_out;

    // workspace layout (adj64 first for 8-B alignment)
    u64* adj64 = (u64*)d_ws;                                   // TENT u64 = 25.6 MB
    int* deg   = (int*)(adj64 + TENT);                         // NN
    int* bc    = deg + NN;                                     // MPAD
    int* offs  = bc + MPAD;                                    // MPAD
    int* bsums = offs + MPAD;                                  // 512
    float* trans = (float*)(bsums + 512);                      // NN*64
    unsigned short* fb16 = (unsigned short*)(trans + (size_t)NN * 64);  // NN*64
    unsigned short* wp = fb16 + (size_t)NN * 64;               // 5*4096

    // zero deg + bc (incl. scan pad)
    hipMemsetAsync(deg, 0, (size_t)(NN + MPAD) * sizeof(int), stream);

    pre_kernel<<<(NN * 16 + 255) / 256, 256, 0, stream>>>(f, (unsigned int*)fb16);
    wprep_kernel<<<(5 * 4096 + 255) / 256, 256, 0, stream>>>(w_in, w_hid, w_out, wp);
    hist_kernel<<<(EE + 255) / 256, 256, 0, stream>>>(esrc, deg);
    bin_count<<<NCH, 256, 0, stream>>>(esrc, edst, bc);
    scan_blocks<<<SC_NB, 512, 0, stream>>>(bc, offs, bsums);
    scan_sums<<<1, 512, 0, stream>>>(bsums);
    add_offsets<<<SC_NB, 512, 0, stream>>>(offs, bsums);
    bin_scatter<<<NCH, 256, 0, stream>>>(esrc, edst, ew, deg, offs, adj64);
    gather_bucket<<<NB, 256, 0, stream>>>(fb16, offs, adj64, xi, trans);
    node_kernel<<<(NN + 127) / 128, 256, 0, stream>>>(
        fb16, f, macro_u, source, xi, wp, b_in, b_hid, b_out, trans, out);
}

// Round 7
// 460.015 us; speedup vs baseline: 3.7235x; 3.7235x over previous
//
#include <hip/hip_runtime.h>

#define NN 100000
#define EE 1600000
#define DTc 0.1f
#define REGc 1e-6f
#define WQc (1.0f / 64.0f)

#define NB 782              // ceil(NN/128) buckets of 128 nodes
#define CHUNK 8192          // edges per binning block
#define NCH 196             // ceil(EE/CHUNK)
#define SC_NB 300           // scan blocks of 512 over the matrix
#define MPAD (SC_NB * 512)  // 153600 >= NB*NCH = 153272 (pad zeroed)
#define TENT (2 * EE)       // combined incidence entries
#define ACT_S 72            // padded LDS row stride (bf16) in node_kernel

typedef unsigned long long u64;
typedef __attribute__((ext_vector_type(8))) short short8;
typedef __attribute__((ext_vector_type(4))) float f32x4;

__device__ __forceinline__ unsigned short f2bf(float x) {
    unsigned u = __float_as_uint(x);
    unsigned r = (u + 0x7fffu + ((u >> 16) & 1u)) >> 16;   // RNE
    return (unsigned short)r;
}
__device__ __forceinline__ float bf2f(unsigned short s) {
    return __uint_as_float(((unsigned)s) << 16);
}

// ---------------------------------------------------------------------------
// f+ = relu(f) as bf16, 4 elems/thread (NN*16 threads)
// ---------------------------------------------------------------------------
__global__ __launch_bounds__(256) void pre_kernel(const float* __restrict__ f,
                                                  unsigned int* __restrict__ fb16u) {
    int i = blockIdx.x * 256 + threadIdx.x;
    if (i < NN * 16) {
        float4 v = *(const float4*)&f[i * 4];
        unsigned lo = (unsigned)f2bf(fmaxf(v.x, 0.f)) | ((unsigned)f2bf(fmaxf(v.y, 0.f)) << 16);
        unsigned hi = (unsigned)f2bf(fmaxf(v.z, 0.f)) | ((unsigned)f2bf(fmaxf(v.w, 0.f)) << 16);
        fb16u[i * 2] = lo;
        fb16u[i * 2 + 1] = hi;
    }
}

// ---------------------------------------------------------------------------
// Weight prep: wp[l][n*64+k] = bf16(W_l[k*64+n])  (transposed, B-frag ready)
// ---------------------------------------------------------------------------
__global__ __launch_bounds__(256) void wprep_kernel(
    const float* __restrict__ w_in, const float* __restrict__ w_hid,
    const float* __restrict__ w_out, unsigned short* __restrict__ wp) {
    int i = blockIdx.x * 256 + threadIdx.x;
    if (i < 5 * 4096) {
        int l = i >> 12, idx = i & 4095;
        int n = idx >> 6, k = idx & 63;
        const float* W = (l == 0) ? w_in : (l < 4 ? w_hid + (l - 1) * 4096 : w_out);
        wp[i] = f2bf(W[k * 64 + n]);
    }
}

// ---------------------------------------------------------------------------
// Out-degree histogram (for q = ew/deg[src])
// ---------------------------------------------------------------------------
__global__ __launch_bounds__(256) void hist_kernel(const int* __restrict__ esrc,
                                                   int* __restrict__ deg) {
    int i = blockIdx.x * 256 + threadIdx.x;
    if (i < EE) atomicAdd(&deg[esrc[i]], 1);
}

// ---------------------------------------------------------------------------
// Per-chunk bucket counts -> bucket-major matrix bc[bucket*NCH + chunk]
// ---------------------------------------------------------------------------
__global__ __launch_bounds__(256) void bin_count(const int* __restrict__ esrc,
                                                 const int* __restrict__ edst,
                                                 int* __restrict__ bc) {
    __shared__ int cnt[NB];
    int t = threadIdx.x;
    for (int j = t; j < NB; j += 256) cnt[j] = 0;
    __syncthreads();
    int base = blockIdx.x * CHUNK;
    int nE = min(CHUNK, EE - base);
    for (int i = t; i < nE; i += 256) {
        atomicAdd(&cnt[esrc[base + i] >> 7], 1);
        atomicAdd(&cnt[edst[base + i] >> 7], 1);
    }
    __syncthreads();
    for (int j = t; j < NB; j += 256) bc[j * NCH + blockIdx.x] = cnt[j];
}

// ---------------------------------------------------------------------------
// 3-kernel exclusive scan over MPAD elements (pad pre-zeroed by memset)
// ---------------------------------------------------------------------------
__global__ __launch_bounds__(512) void scan_blocks(const int* __restrict__ in,
                                                   int* __restrict__ out,
                                                   int* __restrict__ bsums) {
    __shared__ int s[512];
    int t = threadIdx.x;
    int i = blockIdx.x * 512 + t;
    int v = in[i];
    s[t] = v;
    __syncthreads();
    for (int o = 1; o < 512; o <<= 1) {
        int x = (t >= o) ? s[t - o] : 0;
        __syncthreads();
        s[t] += x;
        __syncthreads();
    }
    out[i] = s[t] - v;
    if (t == 0) bsums[blockIdx.x] = s[511];
}

__global__ __launch_bounds__(512) void scan_sums(int* __restrict__ bsums) {
    __shared__ int s[512];
    int t = threadIdx.x;
    int v = (t < SC_NB) ? bsums[t] : 0;
    s[t] = v;
    __syncthreads();
    for (int o = 1; o < 512; o <<= 1) {
        int x = (t >= o) ? s[t - o] : 0;
        __syncthreads();
        s[t] += x;
        __syncthreads();
    }
    if (t < SC_NB) bsums[t] = s[t] - v;
}

__global__ __launch_bounds__(512) void add_offsets(int* __restrict__ offs,
                                                   const int* __restrict__ bsums) {
    int i = blockIdx.x * 512 + threadIdx.x;
    offs[i] += bsums[blockIdx.x];
}

// ---------------------------------------------------------------------------
// Binned scatter: chunk re-reads its edges, appends entries into its PRIVATE
// [chunk][bucket] ranges via LDS cursors. entry = (f32 q)<<32 | local<<17 | other
// ---------------------------------------------------------------------------
__global__ __launch_bounds__(256) void bin_scatter(
    const int* __restrict__ esrc, const int* __restrict__ edst,
    const float* __restrict__ ew, const int* __restrict__ deg,
    const int* __restrict__ offs, u64* __restrict__ adj64) {
    __shared__ int cur[NB];
    int t = threadIdx.x, blk = blockIdx.x;
    for (int j = t; j < NB; j += 256) cur[j] = offs[j * NCH + blk];
    __syncthreads();
    int base = blk * CHUNK;
    int nE = min(CHUNK, EE - base);
    for (int i = t; i < nE; i += 256) {
        int s = esrc[base + i], d = edst[base + i];
        float q = ew[base + i] / (float)deg[s];
        u64 qb = ((u64)__float_as_uint(q)) << 32;
        int p1 = atomicAdd(&cur[s >> 7], 1);
        adj64[p1] = qb | (unsigned)(d | ((s & 127) << 17));
        int p2 = atomicAdd(&cur[d >> 7], 1);
        adj64[p2] = qb | (unsigned)(s | ((d & 127) << 17));
    }
}

// ---------------------------------------------------------------------------
// Per-bucket sort: one block per 128-node bucket. Pass 1: count per-node in
// LDS + 128-wide scan -> node_offs. Pass 2: re-read entries, write 4B packed
// (q15<<17 | other) into node-sorted positions (all inside the bucket's own
// ~16 KB adj4 window -> L2-hot writes).
// ---------------------------------------------------------------------------
__global__ __launch_bounds__(256) void bucket_sort(
    const int* __restrict__ offs, const u64* __restrict__ adj64,
    unsigned int* __restrict__ adj4, int* __restrict__ node_offs) {
    __shared__ int cnt[128], sc[128], base[128];
    int t = threadIdx.x, b = blockIdx.x;
    if (t < 128) cnt[t] = 0;
    __syncthreads();
    int start = offs[b * NCH];
    int end = offs[(b + 1) * NCH];          // b=NB-1 reads zero-padded tail -> TENT
    for (int i = start + t; i < end; i += 256) {
        int local = ((unsigned)adj64[i] >> 17) & 127;
        atomicAdd(&cnt[local], 1);
    }
    __syncthreads();
    if (t < 128) sc[t] = cnt[t];
    __syncthreads();
    for (int o = 1; o < 128; o <<= 1) {
        int x = 0;
        if (t < 128 && t >= o) x = sc[t - o];
        __syncthreads();
        if (t < 128) sc[t] += x;
        __syncthreads();
    }
    if (t < 128) {
        base[t] = start + sc[t] - cnt[t];   // exclusive
        int n = b * 128 + t;
        if (n < NN) node_offs[n] = base[t];
        cnt[t] = 0;                          // reuse as cursor
    }
    if (b == 0 && t == 0) node_offs[NN] = TENT;
    __syncthreads();
    for (int i = start + t; i < end; i += 256) {
        u64 e = adj64[i];
        unsigned lo = (unsigned)e;
        int local = (lo >> 17) & 127;
        float q = __uint_as_float((unsigned)(e >> 32));
        unsigned q15 = (unsigned)(q * 32768.f + 0.5f);
        if (q15 > 32767u) q15 = 32767u;
        int p = base[local] + atomicAdd(&cnt[local], 1);
        adj4[p] = (q15 << 17) | (lo & 0x1FFFFu);
    }
}

// ---------------------------------------------------------------------------
// Gather transport: one wave per node, lane = bin; unroll-4 (R5-proven).
// ---------------------------------------------------------------------------
__global__ __launch_bounds__(256) void gather_kernel(
    const unsigned short* __restrict__ fb16, const int* __restrict__ node_offs,
    const unsigned int* __restrict__ adj, const float* __restrict__ xi,
    float* __restrict__ trans) {
    const float QS = 1.f / 32768.f;
    int lane = threadIdx.x & 63;
    int n = blockIdx.x * 4 + (threadIdx.x >> 6);
    if (n >= NN) return;
    int j = node_offs[n];
    int end = node_offs[n + 1];
    float a0 = 0.f, a1 = 0.f, a2 = 0.f, a3 = 0.f, qs = 0.f;
    for (; j + 4 <= end; j += 4) {
        unsigned v0 = adj[j], v1 = adj[j + 1], v2 = adj[j + 2], v3 = adj[j + 3];
        float f0 = bf2f(fb16[(v0 & 0x1FFFFu) * 64 + lane]);
        float f1 = bf2f(fb16[(v1 & 0x1FFFFu) * 64 + lane]);
        float f2 = bf2f(fb16[(v2 & 0x1FFFFu) * 64 + lane]);
        float f3 = bf2f(fb16[(v3 & 0x1FFFFu) * 64 + lane]);
        float q0 = (float)(v0 >> 17) * QS;
        float q1 = (float)(v1 >> 17) * QS;
        float q2 = (float)(v2 >> 17) * QS;
        float q3 = (float)(v3 >> 17) * QS;
        a0 = fmaf(q0, f0, a0);
        a1 = fmaf(q1, f1, a1);
        a2 = fmaf(q2, f2, a2);
        a3 = fmaf(q3, f3, a3);
        qs += (q0 + q1) + (q2 + q3);
    }
    for (; j < end; j++) {
        unsigned v0 = adj[j];
        float q0 = (float)(v0 >> 17) * QS;
        a0 = fmaf(q0, bf2f(fb16[(v0 & 0x1FFFFu) * 64 + lane]), a0);
        qs += q0;
    }
    float acc = (a0 + a1) + (a2 + a3);
    float fn = bf2f(fb16[n * 64 + lane]);
    trans[n * 64 + lane] = xi[lane] * (acc - qs * fn);
}

// ---------------------------------------------------------------------------
// MFMA node kernel (R5-proven): 256 thr / 4 waves / 128 nodes, barrier-free
// layer loop, wave-private act rows, pre-transposed bf16 weights from global.
// ---------------------------------------------------------------------------
__global__ __launch_bounds__(256) void node_kernel(
    const unsigned short* __restrict__ fb16, const float* __restrict__ f,
    const float* __restrict__ macro_u, const float* __restrict__ source,
    const float* __restrict__ xi, const unsigned short* __restrict__ wp,
    const float* __restrict__ b_in, const float* __restrict__ b_hid,
    const float* __restrict__ b_out,
    const float* __restrict__ trans, float* __restrict__ out) {
    __shared__ __attribute__((aligned(16))) unsigned short act[128 * ACT_S];
    __shared__ float s0s[128], s1s[128], us[128], xif[64];

    const int t = threadIdx.x;
    const int wid = t >> 6;
    const int lane = t & 63;
    const int m = lane & 15;
    const int quad = lane >> 4;
    const int nodeBase = blockIdx.x * 128;
    const int gbase = nodeBase * 64;

    if (t < 128) {
        int n = nodeBase + t;
        us[t] = (n < NN) ? macro_u[n] : 0.f;
    }
    if (t < 64) xif[t] = xi[t];

#pragma unroll
    for (int i = 0; i < 8; i++) {
        int r = wid * 32 + i * 4 + (lane >> 4);
        int c = (lane & 15) * 4;
        uint2 v = {0u, 0u};
        if (nodeBase + r < NN) v = *(const uint2*)&fb16[gbase + r * 64 + c];
        *(uint2*)&act[r * ACT_S + c] = v;
    }

    const int rowbase = wid * 32;

    for (int l = 0; l < 5; l++) {
        const unsigned short* W = wp + l * 4096;
        const float* B = (l == 0) ? b_in : (l < 4 ? b_hid + (l - 1) * 64 : b_out);

        short8 Af[2][2], Bf[4][2];
#pragma unroll
        for (int rt = 0; rt < 2; rt++)
#pragma unroll
            for (int kk = 0; kk < 2; kk++)
                Af[rt][kk] = *(const short8*)&act[(rowbase + rt * 16 + m) * ACT_S + kk * 32 + quad * 8];
#pragma unroll
        for (int ct = 0; ct < 4; ct++)
#pragma unroll
            for (int kk = 0; kk < 2; kk++)
                Bf[ct][kk] = *(const short8*)&W[(ct * 16 + m) * 64 + kk * 32 + quad * 8];

        f32x4 acc[2][4];
#pragma unroll
        for (int rt = 0; rt < 2; rt++)
#pragma unroll
            for (int ct = 0; ct < 4; ct++) {
                acc[rt][ct] = (f32x4){0.f, 0.f, 0.f, 0.f};
                acc[rt][ct] = __builtin_amdgcn_mfma_f32_16x16x32_bf16(Af[rt][0], Bf[ct][0], acc[rt][ct], 0, 0, 0);
                acc[rt][ct] = __builtin_amdgcn_mfma_f32_16x16x32_bf16(Af[rt][1], Bf[ct][1], acc[rt][ct], 0, 0, 0);
            }

#pragma unroll
        for (int rt = 0; rt < 2; rt++)
#pragma unroll
            for (int ct = 0; ct < 4; ct++) {
                float bv = B[ct * 16 + m];
#pragma unroll
                for (int r = 0; r < 4; r++) {
                    int row = rowbase + rt * 16 + quad * 4 + r;
                    float val = acc[rt][ct][r] + bv;
                    val = (l < 4) ? fmaxf(val, 0.f) : tanhf(val);
                    act[row * ACT_S + ct * 16 + m] = f2bf(val);
                }
            }
    }
    __syncthreads();

    if (t < 128) {
        float u = us[t];
        float v0 = 0.f, v1 = 0.f, sxs2 = 0.f, sxi = 0.f;
        const short8* rp = (const short8*)&act[t * ACT_S];
#pragma unroll
        for (int c = 0; c < 8; c++) {
            short8 v = rp[c];
#pragma unroll
            for (int jj = 0; jj < 8; jj++) {
                float om = bf2f((unsigned short)v[jj]);
                float xv = xif[c * 8 + jj];
                float xs = xv + u;
                v0 += om;
                v1 += xs * om;
                sxs2 += xs * xs;
                sxi += xv;
            }
        }
        v0 *= WQc;
        v1 *= WQc;
        float c00 = WQc + REGc;
        float c01 = WQc * WQc * (sxi + 64.f * u);
        float c11 = WQc * WQc * sxs2 + REGc;
        float det = c00 * c11 - c01 * c01;
        float inv = 1.0f / det;
        s0s[t] = (c11 * v0 - c01 * v1) * inv;
        s1s[t] = (c00 * v1 - c01 * v0) * inv;
    }
    __syncthreads();

#pragma unroll
    for (int i = 0; i < 8; i++) {
        int e = (i * 256 + t) * 4;
        int nl = e >> 6;
        if (nodeBase + nl < NN) {
            int g = gbase + e;
            int c0 = e & 63;
            float4 fv = *(const float4*)&f[g];
            float4 sv = *(const float4*)&source[g];
            float4 tv = *(const float4*)&trans[g];
            float uu = us[nl];
            float sv0 = s0s[nl], sv1 = s1s[nl];
            float4 ov;
            float* ovp = (float*)&ov;
            const float* fp = (const float*)&fv;
            const float* sp = (const float*)&sv;
            const float* tp = (const float*)&tv;
#pragma unroll
            for (int jj = 0; jj < 4; jj++) {
                float om = bf2f(act[nl * ACT_S + c0 + jj]);
                float xs = xif[c0 + jj] + uu;
                float omst = om - WQc * (sv0 + xs * sv1);
                float val = fmaxf(fp[jj], 0.f) + DTc * (sp[jj] + omst - tp[jj]);
                ovp[jj] = fmaxf(val, 0.f);
            }
            *(float4*)&out[g] = ov;
        }
    }
}

extern "C" void kernel_launch(void* const* d_in, const int* in_sizes, int n_in,
                              void* d_out, int out_size, void* d_ws, size_t ws_size,
                              hipStream_t stream) {
    const float* f       = (const float*)d_in[0];
    const float* macro_u = (const float*)d_in[1];
    const float* source  = (const float*)d_in[2];
    const int*   esrc    = (const int*)d_in[3];
    const int*   edst    = (const int*)d_in[4];
    const float* ew      = (const float*)d_in[5];
    const float* xi      = (const float*)d_in[6];
    const float* w_in    = (const float*)d_in[7];
    const float* b_in    = (const float*)d_in[8];
    const float* w_hid   = (const float*)d_in[9];
    const float* b_hid   = (const float*)d_in[10];
    const float* w_out   = (const float*)d_in[11];
    const float* b_out   = (const float*)d_in[12];
    float* out = (float*)d_out;

    // workspace layout (8-byte entries first)
    u64* adj64 = (u64*)d_ws;                                   // TENT u64 = 25.6 MB
    unsigned int* adj4 = (unsigned int*)(adj64 + TENT);        // TENT u32 = 12.8 MB
    int* deg   = (int*)(adj4 + TENT);                          // NN
    int* bc    = deg + NN;                                     // MPAD
    int* offs  = bc + MPAD;                                    // MPAD
    int* bsums = offs + MPAD;                                  // 512
    int* node_offs = bsums + 512;                              // NN+1 (+pad)
    float* trans = (float*)(node_offs + NN + 8);               // NN*64
    unsigned short* fb16 = (unsigned short*)(trans + (size_t)NN * 64);  // NN*64
    unsigned short* wp = fb16 + (size_t)NN * 64;               // 5*4096

    // zero deg + bc (incl. scan pad)
    hipMemsetAsync(deg, 0, (size_t)(NN + MPAD) * sizeof(int), stream);

    pre_kernel<<<(NN * 16 + 255) / 256, 256, 0, stream>>>(f, (unsigned int*)fb16);
    wprep_kernel<<<(5 * 4096 + 255) / 256, 256, 0, stream>>>(w_in, w_hid, w_out, wp);
    hist_kernel<<<(EE + 255) / 256, 256, 0, stream>>>(esrc, deg);
    bin_count<<<NCH, 256, 0, stream>>>(esrc, edst, bc);
    scan_blocks<<<SC_NB, 512, 0, stream>>>(bc, offs, bsums);
    scan_sums<<<1, 512, 0, stream>>>(bsums);
    add_offsets<<<SC_NB, 512, 0, stream>>>(offs, bsums);
    bin_scatter<<<NCH, 256, 0, stream>>>(esrc, edst, ew, deg, offs, adj64);
    bucket_sort<<<NB, 256, 0, stream>>>(offs, adj64, adj4, node_offs);
    gather_kernel<<<(NN + 3) / 4, 256, 0, stream>>>(fb16, node_offs, adj4, xi, trans);
    node_kernel<<<(NN + 127) / 128, 256, 0, stream>>>(
        fb16, f, macro_u, source, xi, wp, b_in, b_hid, b_out, trans, out);
}

// Round 8
// 400.915 us; speedup vs baseline: 4.2724x; 1.1474x over previous
//
#include <hip/hip_runtime.h>

#define NN 100000
#define EE 1600000
#define DTc 0.1f
#define REGc 1e-6f
#define WQc (1.0f / 64.0f)

#define NB 782              // ceil(NN/128) buckets of 128 nodes
#define CHUNK 8192          // edges per binning block
#define NCH 196             // ceil(EE/CHUNK)
#define SC_NB 300           // scan blocks of 512 over the matrix
#define MPAD (SC_NB * 512)  // 153600 >= NB*NCH = 153272 (pad zeroed)
#define TENT (2 * EE)       // combined incidence entries
#define ACT_S 72            // padded LDS row stride (bf16) in node_kernel
#define PRE_NB 6250         // NN*16/256 exact
#define WP_NB 80            // 5*4096/256 exact

typedef unsigned long long u64;
typedef __attribute__((ext_vector_type(8))) short short8;
typedef __attribute__((ext_vector_type(4))) float f32x4;

__device__ __forceinline__ unsigned short f2bf(float x) {
    unsigned u = __float_as_uint(x);
    unsigned r = (u + 0x7fffu + ((u >> 16) & 1u)) >> 16;   // RNE
    return (unsigned short)r;
}
__device__ __forceinline__ float bf2f(unsigned short s) {
    return __uint_as_float(((unsigned)s) << 16);
}

// ---------------------------------------------------------------------------
// Merged prep: blocks [0,PRE_NB) -> f+ = relu(f) as bf16 (4 elems/thread);
// blocks [PRE_NB, PRE_NB+WP_NB) -> transposed bf16 weights.
// ---------------------------------------------------------------------------
__global__ __launch_bounds__(256) void prep_kernel(
    const float* __restrict__ f, unsigned int* __restrict__ fb16u,
    const float* __restrict__ w_in, const float* __restrict__ w_hid,
    const float* __restrict__ w_out, unsigned short* __restrict__ wp) {
    int b = blockIdx.x;
    if (b < PRE_NB) {
        int i = b * 256 + threadIdx.x;          // < NN*16 exactly
        float4 v = *(const float4*)&f[i * 4];
        unsigned lo = (unsigned)f2bf(fmaxf(v.x, 0.f)) | ((unsigned)f2bf(fmaxf(v.y, 0.f)) << 16);
        unsigned hi = (unsigned)f2bf(fmaxf(v.z, 0.f)) | ((unsigned)f2bf(fmaxf(v.w, 0.f)) << 16);
        fb16u[i * 2] = lo;
        fb16u[i * 2 + 1] = hi;
    } else {
        int i = (b - PRE_NB) * 256 + threadIdx.x;   // < 5*4096 exactly
        int l = i >> 12, idx = i & 4095;
        int n = idx >> 6, k = idx & 63;
        const float* W = (l == 0) ? w_in : (l < 4 ? w_hid + (l - 1) * 4096 : w_out);
        wp[i] = f2bf(W[k * 64 + n]);
    }
}

// ---------------------------------------------------------------------------
// Per-chunk bucket counts -> bc[bucket*NCH + chunk]; fused out-degree hist.
// ---------------------------------------------------------------------------
__global__ __launch_bounds__(256) void bin_count(const int* __restrict__ esrc,
                                                 const int* __restrict__ edst,
                                                 int* __restrict__ bc,
                                                 int* __restrict__ deg) {
    __shared__ int cnt[NB];
    int t = threadIdx.x;
    for (int j = t; j < NB; j += 256) cnt[j] = 0;
    __syncthreads();
    int base = blockIdx.x * CHUNK;
    int nE = min(CHUNK, EE - base);
    for (int i = t; i < nE; i += 256) {
        int s = esrc[base + i], d = edst[base + i];
        atomicAdd(&cnt[s >> 7], 1);
        atomicAdd(&cnt[d >> 7], 1);
        atomicAdd(&deg[s], 1);
    }
    __syncthreads();
    for (int j = t; j < NB; j += 256) bc[j * NCH + blockIdx.x] = cnt[j];
}

// ---------------------------------------------------------------------------
// 3-kernel exclusive scan over MPAD elements (pad pre-zeroed by memset)
// ---------------------------------------------------------------------------
__global__ __launch_bounds__(512) void scan_blocks(const int* __restrict__ in,
                                                   int* __restrict__ out,
                                                   int* __restrict__ bsums) {
    __shared__ int s[512];
    int t = threadIdx.x;
    int i = blockIdx.x * 512 + t;
    int v = in[i];
    s[t] = v;
    __syncthreads();
    for (int o = 1; o < 512; o <<= 1) {
        int x = (t >= o) ? s[t - o] : 0;
        __syncthreads();
        s[t] += x;
        __syncthreads();
    }
    out[i] = s[t] - v;
    if (t == 0) bsums[blockIdx.x] = s[511];
}

__global__ __launch_bounds__(512) void scan_sums(int* __restrict__ bsums) {
    __shared__ int s[512];
    int t = threadIdx.x;
    int v = (t < SC_NB) ? bsums[t] : 0;
    s[t] = v;
    __syncthreads();
    for (int o = 1; o < 512; o <<= 1) {
        int x = (t >= o) ? s[t - o] : 0;
        __syncthreads();
        s[t] += x;
        __syncthreads();
    }
    if (t < SC_NB) bsums[t] = s[t] - v;
}

__global__ __launch_bounds__(512) void add_offsets(int* __restrict__ offs,
                                                   const int* __restrict__ bsums) {
    int i = blockIdx.x * 512 + threadIdx.x;
    offs[i] += bsums[blockIdx.x];
}

// ---------------------------------------------------------------------------
// Binned scatter: chunk re-reads its edges, appends entries into its PRIVATE
// [chunk][bucket] ranges via LDS cursors. entry = (f32 q)<<32 | local<<17 | other
// ---------------------------------------------------------------------------
__global__ __launch_bounds__(256) void bin_scatter(
    const int* __restrict__ esrc, const int* __restrict__ edst,
    const float* __restrict__ ew, const int* __restrict__ deg,
    const int* __restrict__ offs, u64* __restrict__ adj64) {
    __shared__ int cur[NB];
    int t = threadIdx.x, blk = blockIdx.x;
    for (int j = t; j < NB; j += 256) cur[j] = offs[j * NCH + blk];
    __syncthreads();
    int base = blk * CHUNK;
    int nE = min(CHUNK, EE - base);
    for (int i = t; i < nE; i += 256) {
        int s = esrc[base + i], d = edst[base + i];
        float q = ew[base + i] / (float)deg[s];
        u64 qb = ((u64)__float_as_uint(q)) << 32;
        int p1 = atomicAdd(&cur[s >> 7], 1);
        adj64[p1] = qb | (unsigned)(d | ((s & 127) << 17));
        int p2 = atomicAdd(&cur[d >> 7], 1);
        adj64[p2] = qb | (unsigned)(s | ((d & 127) << 17));
    }
}

// ---------------------------------------------------------------------------
// Per-bucket sort -> per-node CSR of 4B packed (q15<<17 | other) entries.
// All writes land in the bucket's own ~16 KB adj4 window (L2-hot).
// ---------------------------------------------------------------------------
__global__ __launch_bounds__(256) void bucket_sort(
    const int* __restrict__ offs, const u64* __restrict__ adj64,
    unsigned int* __restrict__ adj4, int* __restrict__ node_offs) {
    __shared__ int cnt[128], sc[128], base[128];
    int t = threadIdx.x, b = blockIdx.x;
    if (t < 128) cnt[t] = 0;
    __syncthreads();
    int start = offs[b * NCH];
    int end = offs[(b + 1) * NCH];          // b=NB-1 reads zero-padded tail -> TENT
    for (int i = start + t; i < end; i += 256) {
        int local = ((unsigned)adj64[i] >> 17) & 127;
        atomicAdd(&cnt[local], 1);
    }
    __syncthreads();
    if (t < 128) sc[t] = cnt[t];
    __syncthreads();
    for (int o = 1; o < 128; o <<= 1) {
        int x = 0;
        if (t < 128 && t >= o) x = sc[t - o];
        __syncthreads();
        if (t < 128) sc[t] += x;
        __syncthreads();
    }
    if (t < 128) {
        base[t] = start + sc[t] - cnt[t];   // exclusive
        int n = b * 128 + t;
        if (n < NN) node_offs[n] = base[t];
        cnt[t] = 0;                          // reuse as cursor
    }
    if (b == 0 && t == 0) node_offs[NN] = TENT;
    __syncthreads();
    for (int i = start + t; i < end; i += 256) {
        u64 e = adj64[i];
        unsigned lo = (unsigned)e;
        int local = (lo >> 17) & 127;
        float q = __uint_as_float((unsigned)(e >> 32));
        unsigned q15 = (unsigned)(q * 32768.f + 0.5f);
        if (q15 > 32767u) q15 = 32767u;
        int p = base[local] + atomicAdd(&cnt[local], 1);
        adj4[p] = (q15 << 17) | (lo & 0x1FFFFu);
    }
}

// ---------------------------------------------------------------------------
// Gather transport: one wave per node, QUARTER-WAVE per entry.
// Lane layout: qt = lane>>4 picks entry j+qt; c = lane&15 loads uint2
// (bins 4c..4c+3). 4 row-loads in flight; q unpacked on 16 lanes not 64.
// Cross-quarter reduce: shfl_xor 16/32, then quarter 0 writes float4.
// ---------------------------------------------------------------------------
__global__ __launch_bounds__(256) void gather_kernel(
    const unsigned int* __restrict__ fb16u, const int* __restrict__ node_offs,
    const unsigned int* __restrict__ adj, const float* __restrict__ xi,
    float* __restrict__ trans) {
    const float QS = 1.f / 32768.f;
    int lane = threadIdx.x & 63;
    int n = blockIdx.x * 4 + (threadIdx.x >> 6);
    if (n >= NN) return;
    int c = lane & 15;     // uint2 column: bins 4c..4c+3
    int qt = lane >> 4;    // quarter index: entry j+qt
    int j = node_offs[n];
    int end = node_offs[n + 1];
    float a0 = 0.f, a1 = 0.f, a2 = 0.f, a3 = 0.f, qs = 0.f;
    for (; j + 4 <= end; j += 4) {
        unsigned e = adj[j + qt];
        uint2 r = *(const uint2*)&fb16u[(e & 0x1FFFFu) * 32 + c * 2];
        float q = (float)(e >> 17) * QS;
        a0 = fmaf(q, __uint_as_float(r.x << 16), a0);
        a1 = fmaf(q, __uint_as_float(r.x & 0xFFFF0000u), a1);
        a2 = fmaf(q, __uint_as_float(r.y << 16), a2);
        a3 = fmaf(q, __uint_as_float(r.y & 0xFFFF0000u), a3);
        qs += q;
    }
    if (j < end) {                       // tail: 1..3 entries, quarter-guarded
        int idx = j + qt;
        bool ok = idx < end;
        unsigned e = ok ? adj[idx] : 0u;
        uint2 r = *(const uint2*)&fb16u[(e & 0x1FFFFu) * 32 + c * 2];
        float q = ok ? (float)(e >> 17) * QS : 0.f;
        a0 = fmaf(q, __uint_as_float(r.x << 16), a0);
        a1 = fmaf(q, __uint_as_float(r.x & 0xFFFF0000u), a1);
        a2 = fmaf(q, __uint_as_float(r.y << 16), a2);
        a3 = fmaf(q, __uint_as_float(r.y & 0xFFFF0000u), a3);
        qs += q;
    }
    a0 += __shfl_xor(a0, 16); a0 += __shfl_xor(a0, 32);
    a1 += __shfl_xor(a1, 16); a1 += __shfl_xor(a1, 32);
    a2 += __shfl_xor(a2, 16); a2 += __shfl_xor(a2, 32);
    a3 += __shfl_xor(a3, 16); a3 += __shfl_xor(a3, 32);
    qs += __shfl_xor(qs, 16); qs += __shfl_xor(qs, 32);
    if (qt == 0) {
        uint2 rn = *(const uint2*)&fb16u[n * 32 + c * 2];
        float4 xv = *(const float4*)&xi[c * 4];
        float4 o;
        o.x = xv.x * (a0 - qs * __uint_as_float(rn.x << 16));
        o.y = xv.y * (a1 - qs * __uint_as_float(rn.x & 0xFFFF0000u));
        o.z = xv.z * (a2 - qs * __uint_as_float(rn.y << 16));
        o.w = xv.w * (a3 - qs * __uint_as_float(rn.y & 0xFFFF0000u));
        *(float4*)&trans[n * 64 + c * 4] = o;
    }
}

// ---------------------------------------------------------------------------
// MFMA node kernel (R5-proven): 256 thr / 4 waves / 128 nodes, barrier-free
// layer loop, wave-private act rows, pre-transposed bf16 weights from global.
// ---------------------------------------------------------------------------
__global__ __launch_bounds__(256) void node_kernel(
    const unsigned short* __restrict__ fb16, const float* __restrict__ f,
    const float* __restrict__ macro_u, const float* __restrict__ source,
    const float* __restrict__ xi, const unsigned short* __restrict__ wp,
    const float* __restrict__ b_in, const float* __restrict__ b_hid,
    const float* __restrict__ b_out,
    const float* __restrict__ trans, float* __restrict__ out) {
    __shared__ __attribute__((aligned(16))) unsigned short act[128 * ACT_S];
    __shared__ float s0s[128], s1s[128], us[128], xif[64];

    const int t = threadIdx.x;
    const int wid = t >> 6;
    const int lane = t & 63;
    const int m = lane & 15;
    const int quad = lane >> 4;
    const int nodeBase = blockIdx.x * 128;
    const int gbase = nodeBase * 64;

    if (t < 128) {
        int n = nodeBase + t;
        us[t] = (n < NN) ? macro_u[n] : 0.f;
    }
    if (t < 64) xif[t] = xi[t];

#pragma unroll
    for (int i = 0; i < 8; i++) {
        int r = wid * 32 + i * 4 + (lane >> 4);
        int c = (lane & 15) * 4;
        uint2 v = {0u, 0u};
        if (nodeBase + r < NN) v = *(const uint2*)&fb16[gbase + r * 64 + c];
        *(uint2*)&act[r * ACT_S + c] = v;
    }

    const int rowbase = wid * 32;

    for (int l = 0; l < 5; l++) {
        const unsigned short* W = wp + l * 4096;
        const float* B = (l == 0) ? b_in : (l < 4 ? b_hid + (l - 1) * 64 : b_out);

        short8 Af[2][2], Bf[4][2];
#pragma unroll
        for (int rt = 0; rt < 2; rt++)
#pragma unroll
            for (int kk = 0; kk < 2; kk++)
                Af[rt][kk] = *(const short8*)&act[(rowbase + rt * 16 + m) * ACT_S + kk * 32 + quad * 8];
#pragma unroll
        for (int ct = 0; ct < 4; ct++)
#pragma unroll
            for (int kk = 0; kk < 2; kk++)
                Bf[ct][kk] = *(const short8*)&W[(ct * 16 + m) * 64 + kk * 32 + quad * 8];

        f32x4 acc[2][4];
#pragma unroll
        for (int rt = 0; rt < 2; rt++)
#pragma unroll
            for (int ct = 0; ct < 4; ct++) {
                acc[rt][ct] = (f32x4){0.f, 0.f, 0.f, 0.f};
                acc[rt][ct] = __builtin_amdgcn_mfma_f32_16x16x32_bf16(Af[rt][0], Bf[ct][0], acc[rt][ct], 0, 0, 0);
                acc[rt][ct] = __builtin_amdgcn_mfma_f32_16x16x32_bf16(Af[rt][1], Bf[ct][1], acc[rt][ct], 0, 0, 0);
            }

#pragma unroll
        for (int rt = 0; rt < 2; rt++)
#pragma unroll
            for (int ct = 0; ct < 4; ct++) {
                float bv = B[ct * 16 + m];
#pragma unroll
                for (int r = 0; r < 4; r++) {
                    int row = rowbase + rt * 16 + quad * 4 + r;
                    float val = acc[rt][ct][r] + bv;
                    val = (l < 4) ? fmaxf(val, 0.f) : tanhf(val);
                    act[row * ACT_S + ct * 16 + m] = f2bf(val);
                }
            }
    }
    __syncthreads();

    if (t < 128) {
        float u = us[t];
        float v0 = 0.f, v1 = 0.f, sxs2 = 0.f, sxi = 0.f;
        const short8* rp = (const short8*)&act[t * ACT_S];
#pragma unroll
        for (int c = 0; c < 8; c++) {
            short8 v = rp[c];
#pragma unroll
            for (int jj = 0; jj < 8; jj++) {
                float om = bf2f((unsigned short)v[jj]);
                float xv = xif[c * 8 + jj];
                float xs = xv + u;
                v0 += om;
                v1 += xs * om;
                sxs2 += xs * xs;
                sxi += xv;
            }
        }
        v0 *= WQc;
        v1 *= WQc;
        float c00 = WQc + REGc;
        float c01 = WQc * WQc * (sxi + 64.f * u);
        float c11 = WQc * WQc * sxs2 + REGc;
        float det = c00 * c11 - c01 * c01;
        float inv = 1.0f / det;
        s0s[t] = (c11 * v0 - c01 * v1) * inv;
        s1s[t] = (c00 * v1 - c01 * v0) * inv;
    }
    __syncthreads();

#pragma unroll
    for (int i = 0; i < 8; i++) {
        int e = (i * 256 + t) * 4;
        int nl = e >> 6;
        if (nodeBase + nl < NN) {
            int g = gbase + e;
            int c0 = e & 63;
            float4 fv = *(const float4*)&f[g];
            float4 sv = *(const float4*)&source[g];
            float4 tv = *(const float4*)&trans[g];
            float uu = us[nl];
            float sv0 = s0s[nl], sv1 = s1s[nl];
            float4 ov;
            float* ovp = (float*)&ov;
            const float* fp = (const float*)&fv;
            const float* sp = (const float*)&sv;
            const float* tp = (const float*)&tv;
#pragma unroll
            for (int jj = 0; jj < 4; jj++) {
                float om = bf2f(act[nl * ACT_S + c0 + jj]);
                float xs = xif[c0 + jj] + uu;
                float omst = om - WQc * (sv0 + xs * sv1);
                float val = fmaxf(fp[jj], 0.f) + DTc * (sp[jj] + omst - tp[jj]);
                ovp[jj] = fmaxf(val, 0.f);
            }
            *(float4*)&out[g] = ov;
        }
    }
}

extern "C" void kernel_launch(void* const* d_in, const int* in_sizes, int n_in,
                              void* d_out, int out_size, void* d_ws, size_t ws_size,
                              hipStream_t stream) {
    const float* f       = (const float*)d_in[0];
    const float* macro_u = (const float*)d_in[1];
    const float* source  = (const float*)d_in[2];
    const int*   esrc    = (const int*)d_in[3];
    const int*   edst    = (const int*)d_in[4];
    const float* ew      = (const float*)d_in[5];
    const float* xi      = (const float*)d_in[6];
    const float* w_in    = (const float*)d_in[7];
    const float* b_in    = (const float*)d_in[8];
    const float* w_hid   = (const float*)d_in[9];
    const float* b_hid   = (const float*)d_in[10];
    const float* w_out   = (const float*)d_in[11];
    const float* b_out   = (const float*)d_in[12];
    float* out = (float*)d_out;

    // workspace layout (8-byte entries first)
    u64* adj64 = (u64*)d_ws;                                   // TENT u64 = 25.6 MB
    unsigned int* adj4 = (unsigned int*)(adj64 + TENT);        // TENT u32 = 12.8 MB
    int* deg   = (int*)(adj4 + TENT);                          // NN
    int* bc    = deg + NN;                                     // MPAD
    int* offs  = bc + MPAD;                                    // MPAD
    int* bsums = offs + MPAD;                                  // 512
    int* node_offs = bsums + 512;                              // NN+1 (+pad)
    float* trans = (float*)(node_offs + NN + 8);               // NN*64
    unsigned short* fb16 = (unsigned short*)(trans + (size_t)NN * 64);  // NN*64
    unsigned short* wp = fb16 + (size_t)NN * 64;               // 5*4096

    // zero deg + bc (incl. scan pad)
    hipMemsetAsync(deg, 0, (size_t)(NN + MPAD) * sizeof(int), stream);

    prep_kernel<<<PRE_NB + WP_NB, 256, 0, stream>>>(f, (unsigned int*)fb16,
                                                    w_in, w_hid, w_out, wp);
    bin_count<<<NCH, 256, 0, stream>>>(esrc, edst, bc, deg);
    scan_blocks<<<SC_NB, 512, 0, stream>>>(bc, offs, bsums);
    scan_sums<<<1, 512, 0, stream>>>(bsums);
    add_offsets<<<SC_NB, 512, 0, stream>>>(offs, bsums);
    bin_scatter<<<NCH, 256, 0, stream>>>(esrc, edst, ew, deg, offs, adj64);
    bucket_sort<<<NB, 256, 0, stream>>>(offs, adj64, adj4, node_offs);
    gather_kernel<<<(NN + 3) / 4, 256, 0, stream>>>((const unsigned int*)fb16,
                                                    node_offs, adj4, xi, trans);
    node_kernel<<<(NN + 127) / 128, 256, 0, stream>>>(
        fb16, f, macro_u, source, xi, wp, b_in, b_hid, b_out, trans, out);
}